// Round 4
// baseline (370.430 us; speedup 1.0000x reference)
//
#include <hip/hip_runtime.h>
#include <hip/hip_bf16.h>

using bf16 = __bf16;
typedef __bf16 bf16x4 __attribute__((ext_vector_type(4)));
typedef __bf16 bf16x8 __attribute__((ext_vector_type(8)));
typedef float f32x4 __attribute__((ext_vector_type(4)));

static constexpr int BATCH = 4;
static constexpr int SEQ   = 2048;
static constexpr int DIN   = 512;
static constexpr int NHEAD = 8;
static constexpr int DMID  = 2048;
static constexpr int MROWS = BATCH * SEQ;   // 8192

// ---------------------------------------------------------------------------
// global -> LDS direct DMA, 16 B per lane (global_load_lds_dwordx4).
// ---------------------------------------------------------------------------
__device__ __forceinline__ void gload16(const void* g, void* l)
{
    __builtin_amdgcn_global_load_lds(
        (const __attribute__((address_space(1))) unsigned int*)g,
        (__attribute__((address_space(3))) unsigned int*)l, 16, 0, 0);
}

// ---------------------------------------------------------------------------
// FUSED: six weight transposes (blocks 0..3071) + mask nonzero check
// (blocks 3072..4095, coalesced 16B/lane runs). Saves one launch; the old
// standalone mask_check had a 256B-strided (uncoalesced) access pattern.
// ---------------------------------------------------------------------------
__global__ __launch_bounds__(256) void tw_mask(
    const float* __restrict__ WQ, const float* __restrict__ WK,
    const float* __restrict__ WV, const float* __restrict__ WO,
    const float* __restrict__ W1, const float* __restrict__ W2,
    bf16* __restrict__ WQt, bf16* __restrict__ WKt, bf16* __restrict__ WVt,
    bf16* __restrict__ WOt, bf16* __restrict__ W1t, bf16* __restrict__ W2t,
    const uint4* __restrict__ mask, int* __restrict__ flag)
{
    const int bid = blockIdx.x;
    if (bid >= 3072) {
        // mask check: 1024 blocks x 256 threads x 16 uint4 (coalesced)
        const uint4* p = mask + (size_t)(bid - 3072) * 4096;
        unsigned nz = 0;
#pragma unroll
        for (int i = 0; i < 16; ++i) {
            const uint4 v = p[i * 256 + threadIdx.x];
            nz |= v.x | v.y | v.z | v.w;
        }
        if (nz) atomicOr(flag, 1);
        return;
    }
    __shared__ float tile[32][33];
    const float* in; bf16* out; int ip, op, cx, ry;
    if (bid < 1024) {
        const int w = bid >> 8, idx = bid & 255;
        in  = w == 0 ? WQ  : w == 1 ? WK  : w == 2 ? WV  : WO;
        out = w == 0 ? WQt : w == 1 ? WKt : w == 2 ? WVt : WOt;
        ip = 512; op = 512; cx = idx & 15; ry = idx >> 4;
    } else if (bid < 2048) {
        const int idx = bid - 1024;
        in = W1; out = W1t; ip = 2048; op = 512; cx = idx & 63; ry = idx >> 6;
    } else {
        const int idx = bid - 2048;
        in = W2; out = W2t; ip = 512; op = 2048; cx = idx & 15; ry = idx >> 4;
    }
    const int c0 = cx * 32, r0 = ry * 32;
    const int tx = threadIdx.x & 31, ty = threadIdx.x >> 5;
    for (int i = 0; i < 32; i += 8)
        tile[ty + i][tx] = in[(size_t)(r0 + ty + i) * ip + c0 + tx];
    __syncthreads();
    for (int i = 0; i < 32; i += 8)
        out[(size_t)(c0 + ty + i) * op + r0 + tx] = (bf16)tile[tx][ty + i];
}

// ---------------------------------------------------------------------------
// 128x128-tile GEMM (m97 structure) for W1 (N=2048). BK=64, 4 waves.
// ---------------------------------------------------------------------------
template <int ACT>
__global__ __launch_bounds__(256) void gemm128(const bf16* __restrict__ A,
                                               const bf16* __restrict__ Bt,
                                               bf16* __restrict__ C,
                                               int N, int K)
{
    __shared__ bf16 sA[128 * 64];
    __shared__ bf16 sB[128 * 64];

    const int t    = threadIdx.x;
    const int lane = t & 63;
    const int wave = t >> 6;
    const int wm   = wave >> 1;
    const int wn   = wave & 1;
    const int lr   = lane & 15;
    const int lq   = lane >> 4;

    const int m0 = blockIdx.y * 128;
    const int n0 = blockIdx.x * 128;

    const int srow = lane >> 3;
    const int scol = (lane & 7) * 8;

    f32x4 acc[4][4] = {};

    for (int k0 = 0; k0 < K; k0 += 64) {
        if (k0) __syncthreads();
#pragma unroll
        for (int i = 0; i < 4; ++i) {
            const int ch = wave * 4 + i;
            const int r  = ch * 8 + srow;
            gload16(A  + (size_t)(m0 + r) * K + k0 + scol, sA + ch * 512);
            gload16(Bt + (size_t)(n0 + r) * K + k0 + scol, sB + ch * 512);
        }
        __syncthreads();

#pragma unroll
        for (int kk = 0; kk < 2; ++kk) {
            bf16x8 af[4], bfr[4];
#pragma unroll
            for (int x = 0; x < 4; ++x) {
                af[x]  = *reinterpret_cast<const bf16x8*>(&sA[(wm * 64 + x * 16 + lr) * 64 + kk * 32 + lq * 8]);
                bfr[x] = *reinterpret_cast<const bf16x8*>(&sB[(wn * 64 + x * 16 + lr) * 64 + kk * 32 + lq * 8]);
            }
#pragma unroll
            for (int m = 0; m < 4; ++m)
#pragma unroll
                for (int n = 0; n < 4; ++n)
                    acc[m][n] = __builtin_amdgcn_mfma_f32_16x16x32_bf16(af[m], bfr[n], acc[m][n], 0, 0, 0);
        }
    }

#pragma unroll
    for (int n = 0; n < 4; ++n) {
        const int col = n0 + wn * 64 + n * 16 + lr;
#pragma unroll
        for (int m = 0; m < 4; ++m) {
            const int rowb = m0 + wm * 64 + m * 16 + lq * 4;
#pragma unroll
            for (int j = 0; j < 4; ++j) {
                float v = acc[m][n][j];
                if (ACT == 1) v = v > 0.f ? v : 0.f;
                C[(size_t)(rowb + j) * N + col] = (bf16)v;
            }
        }
    }
}

// ---------------------------------------------------------------------------
// QKV projection (fp32 A, 64x128 tile) with V written TRANSPOSED directly
// to Vt (kills the separate transpose_b2b launch + 17 MB round-trip).
// ---------------------------------------------------------------------------
__global__ __launch_bounds__(256) void gemm64_qkv(const float* __restrict__ q,
                                                  const float* __restrict__ k,
                                                  const float* __restrict__ v,
                                                  const bf16* __restrict__ WQt,
                                                  const bf16* __restrict__ WKt,
                                                  const bf16* __restrict__ WVt,
                                                  bf16* __restrict__ Qb,
                                                  bf16* __restrict__ Kb,
                                                  bf16* __restrict__ Vt)
{
    __shared__ bf16 sA[64 * 64];
    __shared__ bf16 sB[128 * 64];

    const float* A  = blockIdx.z == 0 ? q   : blockIdx.z == 1 ? k   : v;
    const bf16*  Bt = blockIdx.z == 0 ? WQt : blockIdx.z == 1 ? WKt : WVt;
    const int K = DIN;

    const int t    = threadIdx.x;
    const int lane = t & 63;
    const int wave = t >> 6;
    const int lr   = lane & 15;
    const int lq   = lane >> 4;

    const int m0 = blockIdx.y * 64;
    const int n0 = blockIdx.x * 128;

    const int srow = lane >> 3;
    const int scol = (lane & 7) * 8;

    f32x4 acc[4][2] = {};

    for (int k0 = 0; k0 < K; k0 += 64) {
        float4 fa[4];
#pragma unroll
        for (int i = 0; i < 2; ++i) {
            const float* p = A + (size_t)(m0 + (wave * 2 + i) * 8 + srow) * K + k0 + scol;
            fa[2 * i]     = *reinterpret_cast<const float4*>(p);
            fa[2 * i + 1] = *reinterpret_cast<const float4*>(p + 4);
        }
        if (k0) __syncthreads();
#pragma unroll
        for (int i = 0; i < 4; ++i) {
            const int ch = wave * 4 + i;
            gload16(Bt + (size_t)(n0 + ch * 8 + srow) * K + k0 + scol, sB + ch * 512);
        }
#pragma unroll
        for (int i = 0; i < 2; ++i) {
            const int r = (wave * 2 + i) * 8 + srow;
            const float4 a = fa[2 * i], b = fa[2 * i + 1];
            bf16x8 hh;
            hh[0] = (bf16)a.x; hh[1] = (bf16)a.y; hh[2] = (bf16)a.z; hh[3] = (bf16)a.w;
            hh[4] = (bf16)b.x; hh[5] = (bf16)b.y; hh[6] = (bf16)b.z; hh[7] = (bf16)b.w;
            *reinterpret_cast<bf16x8*>(&sA[r * 64 + scol]) = hh;
        }
        __syncthreads();

#pragma unroll
        for (int kk = 0; kk < 2; ++kk) {
            bf16x8 af[4], bfr[2];
#pragma unroll
            for (int x = 0; x < 4; ++x)
                af[x] = *reinterpret_cast<const bf16x8*>(&sA[(x * 16 + lr) * 64 + kk * 32 + lq * 8]);
#pragma unroll
            for (int n = 0; n < 2; ++n)
                bfr[n] = *reinterpret_cast<const bf16x8*>(&sB[(wave * 32 + n * 16 + lr) * 64 + kk * 32 + lq * 8]);
#pragma unroll
            for (int m = 0; m < 4; ++m)
#pragma unroll
                for (int n = 0; n < 2; ++n)
                    acc[m][n] = __builtin_amdgcn_mfma_f32_16x16x32_bf16(af[m], bfr[n], acc[m][n], 0, 0, 0);
        }
    }

    if (blockIdx.z < 2) {
        bf16* C = blockIdx.z == 0 ? Qb : Kb;
#pragma unroll
        for (int n = 0; n < 2; ++n) {
            const int col = n0 + wave * 32 + n * 16 + lr;
#pragma unroll
            for (int m = 0; m < 4; ++m) {
                const int rowb = m0 + m * 16 + lq * 4;
#pragma unroll
                for (int j = 0; j < 4; ++j)
                    C[(size_t)(rowb + j) * DIN + col] = (bf16)acc[m][n][j];
            }
        }
    } else {
        // V: transpose through LDS (reuse sB), write Vt[hd][l] coalesced.
        __syncthreads();   // all MFMA reads of sB finished
#pragma unroll
        for (int n = 0; n < 2; ++n)
#pragma unroll
            for (int m = 0; m < 4; ++m)
#pragma unroll
                for (int j = 0; j < 4; ++j)
                    sB[(wave * 32 + n * 16 + lr) * 64 + m * 16 + lq * 4 + j] = (bf16)acc[m][n][j];
        __syncthreads();
        const int c = t >> 1, half = t & 1;
#pragma unroll
        for (int qq = 0; qq < 4; ++qq) {
            const bf16x8 vv = *reinterpret_cast<const bf16x8*>(&sB[c * 64 + half * 32 + qq * 8]);
            *reinterpret_cast<bf16x8*>(Vt + (size_t)(n0 + c) * MROWS + m0 + half * 32 + qq * 8) = vv;
        }
    }
}

// ---------------------------------------------------------------------------
// Flash attention — UNCHANGED from round 3 (control variable this round).
// Tripwire: ~86.5 us, FETCH 12.4 MB, WRITE 8.2 MB, conflicts 7.34e6.
// ---------------------------------------------------------------------------
__global__ __launch_bounds__(256) void attn_kernel(const bf16* __restrict__ Qb,
                                                   const bf16* __restrict__ Kb,
                                                   const bf16* __restrict__ Vt,
                                                   const float* __restrict__ mask,
                                                   bf16* __restrict__ O,
                                                   const int* __restrict__ mzf)
{
    const int bi   = blockIdx.x;
    const int xcd  = bi & 7;
    const int slot = bi >> 3;
    const int pair = xcd * 4 + (slot >> 4);
    const int qt   = slot & 15;
    const int h    = pair >> 2;
    const int b    = pair & 3;

    const int t    = threadIdx.x;
    const int lane = t & 63;
    const int wave = t >> 6;
    const int lr   = lane & 15;
    const int lq   = lane >> 4;
    const int q0   = qt * 128;
    const bool useM = (*mzf != 0);

    __shared__ bf16 sK[64 * 72];
    __shared__ bf16 sV[64 * 72];
    __shared__ bf16 sP[4][32 * 72];
    __shared__ bf16 sM[128 * 68];

    bf16x8 qf[2][2];
#pragma unroll
    for (int g = 0; g < 2; ++g) {
        const int qrow = q0 + wave * 32 + g * 16 + lr;
        const bf16* qp = Qb + (size_t)(b * SEQ + qrow) * DIN + h * 64 + lq * 8;
        qf[g][0] = *reinterpret_cast<const bf16x8*>(qp);
        qf[g][1] = *reinterpret_cast<const bf16x8*>(qp + 32);
    }

    f32x4 o[2][4] = {};
    f32x4 lrow[2] = {};

    const int sr = t >> 2;
    const int sc = (t & 3) << 3;

    const bf16*  kbase = Kb + (size_t)(b * SEQ) * DIN + h * 64;
    const bf16*  vbase = Vt + (size_t)(h * 64 + sr) * MROWS + b * SEQ;
    const float* mbase = mask + ((size_t)b * SEQ + q0) * SEQ;

    constexpr float L2E = 1.4426950408889634f;
    constexpr float SCL = 0.125f * L2E;
    const bf16x8 ones = {(bf16)1.f, (bf16)1.f, (bf16)1.f, (bf16)1.f,
                         (bf16)1.f, (bf16)1.f, (bf16)1.f, (bf16)1.f};

    int4 kr0 = *reinterpret_cast<const int4*>(kbase + (size_t)sr * DIN + sc);
    int4 kr1 = *reinterpret_cast<const int4*>(kbase + (size_t)sr * DIN + sc + 32);
    int4 vr0 = *reinterpret_cast<const int4*>(vbase + sc);
    int4 vr1 = *reinterpret_cast<const int4*>(vbase + sc + 32);

    for (int tile = 0; tile < SEQ / 64; ++tile) {
        if (tile) __syncthreads();

        *reinterpret_cast<int4*>(&sK[sr * 72 + sc])      = kr0;
        *reinterpret_cast<int4*>(&sK[sr * 72 + sc + 32]) = kr1;
        *reinterpret_cast<int4*>(&sV[sr * 72 + sc])      = vr0;
        *reinterpret_cast<int4*>(&sV[sr * 72 + sc + 32]) = vr1;
        if (useM) {
            const int k0 = tile * 64;
#pragma unroll
            for (int i = 0; i < 8; ++i) {
                const int idx = t + 256 * i;
                const float4 mr = *reinterpret_cast<const float4*>(
                    mbase + (size_t)(idx >> 4) * SEQ + k0 + (idx & 15) * 4);
                bf16x4 mv;
                mv[0] = (bf16)(mr.x * L2E); mv[1] = (bf16)(mr.y * L2E);
                mv[2] = (bf16)(mr.z * L2E); mv[3] = (bf16)(mr.w * L2E);
                *reinterpret_cast<bf16x4*>(&sM[(idx >> 4) * 68 + (idx & 15) * 4]) = mv;
            }
        }

        if (tile + 1 < SEQ / 64) {
            const int k0 = (tile + 1) * 64;
            kr0 = *reinterpret_cast<const int4*>(kbase + (size_t)(k0 + sr) * DIN + sc);
            kr1 = *reinterpret_cast<const int4*>(kbase + (size_t)(k0 + sr) * DIN + sc + 32);
            vr0 = *reinterpret_cast<const int4*>(vbase + k0 + sc);
            vr1 = *reinterpret_cast<const int4*>(vbase + k0 + sc + 32);
        }
        __syncthreads();

        bf16x8 kf[2][4];
#pragma unroll
        for (int s = 0; s < 2; ++s)
#pragma unroll
            for (int ni = 0; ni < 4; ++ni)
                kf[s][ni] = *reinterpret_cast<const bf16x8*>(&sK[(ni * 16 + lr) * 72 + s * 32 + lq * 8]);

#pragma unroll
        for (int g = 0; g < 2; ++g) {
            f32x4 sf[4] = {};
#pragma unroll
            for (int s = 0; s < 2; ++s)
#pragma unroll
                for (int ni = 0; ni < 4; ++ni)
                    sf[ni] = __builtin_amdgcn_mfma_f32_16x16x32_bf16(qf[g][s], kf[s][ni], sf[ni], 0, 0, 0);

            if (useM) {
#pragma unroll
                for (int j = 0; j < 4; ++j) {
                    const int mr2 = (wave * 32 + g * 16 + lq * 4 + j) * 68;
#pragma unroll
                    for (int ni = 0; ni < 4; ++ni) {
                        const float mval = (float)sM[mr2 + ni * 16 + lr];
                        sP[wave][(g * 16 + lq * 4 + j) * 72 + ni * 16 + lr] = (bf16)exp2f(sf[ni][j] * SCL + mval);
                    }
                }
            } else {
#pragma unroll
                for (int j = 0; j < 4; ++j)
#pragma unroll
                    for (int ni = 0; ni < 4; ++ni)
                        sP[wave][(g * 16 + lq * 4 + j) * 72 + ni * 16 + lr] = (bf16)exp2f(sf[ni][j] * SCL);
            }
        }

        bf16x8 vf[2][4];
#pragma unroll
        for (int s = 0; s < 2; ++s)
#pragma unroll
            for (int ni = 0; ni < 4; ++ni)
                vf[s][ni] = *reinterpret_cast<const bf16x8*>(&sV[(ni * 16 + lr) * 72 + s * 32 + lq * 8]);

#pragma unroll
        for (int g = 0; g < 2; ++g) {
            f32x4 rs = {};
#pragma unroll
            for (int s = 0; s < 2; ++s) {
                bf16x8 pf = *reinterpret_cast<const bf16x8*>(&sP[wave][(g * 16 + lr) * 72 + s * 32 + lq * 8]);
                rs = __builtin_amdgcn_mfma_f32_16x16x32_bf16(pf, ones, rs, 0, 0, 0);
#pragma unroll
                for (int ni = 0; ni < 4; ++ni)
                    o[g][ni] = __builtin_amdgcn_mfma_f32_16x16x32_bf16(pf, vf[s][ni], o[g][ni], 0, 0, 0);
            }
#pragma unroll
            for (int j = 0; j < 4; ++j)
                lrow[g][j] += rs[j];
        }
    }

#pragma unroll
    for (int g = 0; g < 2; ++g)
#pragma unroll
        for (int ni = 0; ni < 4; ++ni)
#pragma unroll
            for (int j = 0; j < 4; ++j) {
                const int row = q0 + wave * 32 + g * 16 + lq * 4 + j;
                const int col = h * 64 + ni * 16 + lr;
                O[(size_t)(b * SEQ + row) * DIN + col] = (bf16)(o[g][ni][j] / lrow[g][j]);
            }
}

// ---------------------------------------------------------------------------
// FUSED GEMM + residual + LayerNorm for N=512 outputs (WO and W2 paths).
// C = A[M,K] @ Bt[512,K]^T; then v = C + X (fp32); LN over the full 512 row.
// Tile: 32 rows x full 512 cols, 8 waves (wave w owns cols w*64).
// Double-buffered LDS (136 KB) with T3-minimum 2-phase order:
//   stage(s+1) issue -> compute(s) -> barrier  (drain hides under MFMA;
//   essential at 1 block/CU where no inter-block overlap exists).
// Outputs: Onb (bf16, nullable) and/or Onf (fp32, nullable).
// ---------------------------------------------------------------------------
__global__ __launch_bounds__(512) void gemm_ln(const bf16* __restrict__ A,
                                               const bf16* __restrict__ Bt,
                                               const float* __restrict__ X,
                                               bf16* __restrict__ Onb,
                                               float* __restrict__ Onf,
                                               int K)
{
    __shared__ bf16 sA[2][32 * 64];     //   8 KB
    __shared__ bf16 sB[2][512 * 64];    // 128 KB
    __shared__ float sRed[32][8];
    __shared__ float sMu[32];
    __shared__ float sRstd[32];

    const int t    = threadIdx.x;
    const int lane = t & 63;
    const int w    = t >> 6;           // 0..7
    const int lr   = lane & 15;
    const int lq   = lane >> 4;
    const int srow = lane >> 3;
    const int scol = (lane & 7) * 8;

    const int m0 = blockIdx.x * 32;

    auto stage = [&](int s, int b) {
        const int k0 = s * 64;
#pragma unroll
        for (int i = 0; i < 8; ++i) {
            const int ch = w * 8 + i;                 // Bt rows ch*8..ch*8+7
            gload16(Bt + (size_t)(ch * 8 + srow) * K + k0 + scol, &sB[b][ch * 512]);
        }
        if (w < 4)
            gload16(A + (size_t)(m0 + w * 8 + srow) * K + k0 + scol, &sA[b][w * 512]);
    };

    f32x4 acc[2][4] = {};
    const int steps = K / 64;

    stage(0, 0);
    __syncthreads();

    for (int s = 0; s < steps; ++s) {
        const int b = s & 1;
        if (s + 1 < steps) stage(s + 1, b ^ 1);

#pragma unroll
        for (int kk = 0; kk < 2; ++kk) {
            bf16x8 af[2], bfr[4];
#pragma unroll
            for (int m = 0; m < 2; ++m)
                af[m] = *reinterpret_cast<const bf16x8*>(&sA[b][(m * 16 + lr) * 64 + kk * 32 + lq * 8]);
#pragma unroll
            for (int n = 0; n < 4; ++n)
                bfr[n] = *reinterpret_cast<const bf16x8*>(&sB[b][(w * 64 + n * 16 + lr) * 64 + kk * 32 + lq * 8]);
#pragma unroll
            for (int m = 0; m < 2; ++m)
#pragma unroll
                for (int n = 0; n < 4; ++n)
                    acc[m][n] = __builtin_amdgcn_mfma_f32_16x16x32_bf16(af[m], bfr[n], acc[m][n], 0, 0, 0);
        }
        __syncthreads();
    }

    // residual add (fp32), in place
#pragma unroll
    for (int m = 0; m < 2; ++m)
#pragma unroll
        for (int n = 0; n < 4; ++n)
#pragma unroll
            for (int j = 0; j < 4; ++j)
                acc[m][n][j] += X[(size_t)(m0 + m * 16 + lq * 4 + j) * DIN + w * 64 + n * 16 + lr];

    // pass 1: row means
#pragma unroll
    for (int m = 0; m < 2; ++m)
#pragma unroll
        for (int j = 0; j < 4; ++j) {
            float s = acc[m][0][j] + acc[m][1][j] + acc[m][2][j] + acc[m][3][j];
            s += __shfl_xor(s, 1); s += __shfl_xor(s, 2);
            s += __shfl_xor(s, 4); s += __shfl_xor(s, 8);
            if (lr == 0) sRed[m * 16 + lq * 4 + j][w] = s;
        }
    __syncthreads();
    if (t < 32) {
        float s = 0.f;
#pragma unroll
        for (int ww = 0; ww < 8; ++ww) s += sRed[t][ww];
        sMu[t] = s * (1.f / DIN);
    }
    __syncthreads();

    // pass 2: row variances
#pragma unroll
    for (int m = 0; m < 2; ++m)
#pragma unroll
        for (int j = 0; j < 4; ++j) {
            const float mu = sMu[m * 16 + lq * 4 + j];
            float s = 0.f;
#pragma unroll
            for (int n = 0; n < 4; ++n) {
                const float d = acc[m][n][j] - mu;
                s += d * d;
            }
            s += __shfl_xor(s, 1); s += __shfl_xor(s, 2);
            s += __shfl_xor(s, 4); s += __shfl_xor(s, 8);
            if (lr == 0) sRed[m * 16 + lq * 4 + j][w] = s;
        }
    __syncthreads();
    if (t < 32) {
        float s = 0.f;
#pragma unroll
        for (int ww = 0; ww < 8; ++ww) s += sRed[t][ww];
        sRstd[t] = rsqrtf(s * (1.f / DIN) + 1e-5f);
    }
    __syncthreads();

    // normalize + write
#pragma unroll
    for (int m = 0; m < 2; ++m)
#pragma unroll
        for (int j = 0; j < 4; ++j) {
            const int rl = m * 16 + lq * 4 + j;
            const float mu = sMu[rl], rstd = sRstd[rl];
            const size_t rowoff = (size_t)(m0 + rl) * DIN;
#pragma unroll
            for (int n = 0; n < 4; ++n) {
                const float r = (acc[m][n][j] - mu) * rstd;
                const int col = w * 64 + n * 16 + lr;
                if (Onb) Onb[rowoff + col] = (bf16)r;
                if (Onf) Onf[rowoff + col] = r;
            }
        }
}

// ---------------------------------------------------------------------------
extern "C" void kernel_launch(void* const* d_in, const int* in_sizes, int n_in,
                              void* d_out, int out_size, void* d_ws, size_t ws_size,
                              hipStream_t stream)
{
    const float* query = (const float*)d_in[0];
    const float* key   = (const float*)d_in[1];
    const float* value = (const float*)d_in[2];
    const float* mask  = (const float*)d_in[3];
    const float* WQ    = (const float*)d_in[4];
    const float* WK    = (const float*)d_in[5];
    const float* WV    = (const float*)d_in[6];
    const float* WO    = (const float*)d_in[7];
    const float* W1    = (const float*)d_in[8];
    const float* W2    = (const float*)d_in[9];

    char* w = (char*)d_ws;
    size_t off = 0;
    auto carve2 = [&](size_t elems) { bf16* p = (bf16*)(w + off); off += elems * 2; return p; };
    auto carve4 = [&](size_t elems) { float* p = (float*)(w + off); off += elems * 4; return p; };

    bf16* Qb    = carve2((size_t)MROWS * DIN);
    bf16* Kb    = carve2((size_t)MROWS * DIN);
    bf16* Vb    = carve2((size_t)MROWS * DIN);   // used as attn output (Ob)
    bf16* Vt    = carve2((size_t)MROWS * DIN);
    bf16* Mid   = carve2((size_t)MROWS * DMID);
    float* Ln1f = carve4((size_t)MROWS * DIN);
    bf16* WQt   = carve2((size_t)DIN * DIN);
    bf16* WKt   = carve2((size_t)DIN * DIN);
    bf16* WVt   = carve2((size_t)DIN * DIN);
    bf16* WOt   = carve2((size_t)DIN * DIN);
    bf16* W1t   = carve2((size_t)DIN * DMID);
    bf16* W2t   = carve2((size_t)DMID * DIN);
    int*  mzf   = (int*)(w + off); off += 16;
    if (off > ws_size) return;

    bf16* Ob   = Vb;   // attn output  (Vb slot never written otherwise now)
    bf16* Ln1b = Kb;   // LN1 bf16     (Kb dead after attention)

    const dim3 blk(256);

    // mask-zero flag
    hipMemsetAsync(mzf, 0, 4, stream);

    // weights transpose + mask check (fused)
    tw_mask<<<dim3(4096), blk, 0, stream>>>(WQ, WK, WV, WO, W1, W2,
                                            WQt, WKt, WVt, WOt, W1t, W2t,
                                            (const uint4*)mask, mzf);

    // Q/K/V projections; V written transposed directly to Vt
    gemm64_qkv<<<dim3(DIN / 128, MROWS / 64, 3), blk, 0, stream>>>(query, key, value,
                                                                   WQt, WKt, WVt, Qb, Kb, Vt);

    // attention (unchanged)
    attn_kernel<<<dim3(512), blk, 0, stream>>>(Qb, Kb, Vt, mask, Ob, mzf);

    // WO projection + residual(query) + LN  -> Ln1b (bf16) + Ln1f (fp32)
    gemm_ln<<<dim3(MROWS / 32), dim3(512), 0, stream>>>(Ob, WOt, query, Ln1b, Ln1f, DIN);

    // FFN up + ReLU
    gemm128<1><<<dim3(DMID / 128, MROWS / 128), blk, 0, stream>>>(Ln1b, W1t, Mid, DMID, DIN);

    // W2 projection + residual(Ln1f) + LN -> fp32 output
    gemm_ln<<<dim3(MROWS / 32), dim3(512), 0, stream>>>(Mid, W2t, Ln1f,
                                                        (bf16*)nullptr, (float*)d_out, DMID);
}